// Round 1
// baseline (199.485 us; speedup 1.0000x reference)
//
#include <hip/hip_runtime.h>
#include <stdint.h>

#define D_DIM 256
#define K_CODES 8192
#define BM 256        // rows per block (4 waves x 64 rows)
#define BN 64         // codes per LDS tile
#define KSPLIT 4      // codebook split across blocks
#define CPB (K_CODES / KSPLIT)   // 2048 codes per block
#define NT (CPB / BN)            // 32 tiles
#define KT 8                     // D/32 k-steps per MFMA chain

typedef float f32x4 __attribute__((ext_vector_type(4)));
typedef short bf16x8 __attribute__((ext_vector_type(8)));
typedef __attribute__((address_space(3))) uint32_t lds_u32_t;
typedef __attribute__((address_space(1))) uint32_t glb_u32_t;

__device__ __forceinline__ ushort f2bf(float f) {
  uint32_t u = __builtin_bit_cast(uint32_t, f);
  return (ushort)((u + 0x7FFFu + ((u >> 16) & 1u)) >> 16);  // RNE
}

// ---------------------------------------------------------------------------
// prep: codebook -> bf16 (pre-swizzled rows) + squared norms.
// Swizzle: within each 512B row, byte_off ^= ((code&7)<<4). Staging copies rows
// linearly into LDS, so LDS ends up swizzled; reader XORs the same mask.
// ---------------------------------------------------------------------------
__global__ void vq_prep(const float* __restrict__ cb, float* __restrict__ cnorm,
                        ushort* __restrict__ cbb) {
  const int lane = threadIdx.x & 63;
  const int code = (blockIdx.x * blockDim.x + threadIdx.x) >> 6;  // one wave per code
  const float4 v = *(const float4*)(cb + (size_t)code * D_DIM + lane * 4);
  float ss = v.x * v.x + v.y * v.y + v.z * v.z + v.w * v.w;
#pragma unroll
  for (int m = 32; m >= 1; m >>= 1) ss += __shfl_xor(ss, m, 64);
  if (lane == 0) cnorm[code] = ss;
  ushort4 b = make_ushort4(f2bf(v.x), f2bf(v.y), f2bf(v.z), f2bf(v.w));
  const int off = (lane * 8) ^ ((code & 7) << 4);  // 8B-aligned stays 8B-aligned
  *(ushort4*)((char*)(cbb + (size_t)code * D_DIM) + off) = b;
}

// ---------------------------------------------------------------------------
// main: fused distance GEMM + argmin.
// Each wave holds 64 x-rows as A fragments in registers (4 frags x 8 ksteps).
// B (codebook tile) streamed via double-buffered LDS with global_load_lds.
// Score = ||c||^2 - 2*dot (row term constant -> dropped for argmin).
// ---------------------------------------------------------------------------
__global__ __launch_bounds__(256, 2) void vq_main(
    const float* __restrict__ x, const ushort* __restrict__ cbb,
    const float* __restrict__ cnorm, unsigned long long* __restrict__ amin) {
  __shared__ ushort lds[2][BN * D_DIM];  // 2 x 32 KB
  const int tid = threadIdx.x;
  const int lane = tid & 63;
  const int wid = tid >> 6;
  const int ks = blockIdx.x & (KSPLIT - 1);
  const int mb = blockIdx.x >> 2;
  const int r0 = mb * BM + wid * 64;

  const ushort* cbk = cbb + (size_t)ks * CPB * D_DIM;

  // stage tile 0 (overlaps with A-fragment loads below)
  {
    const char* src = (const char*)cbk;
#pragma unroll
    for (int i = 0; i < 8; i++)
      __builtin_amdgcn_global_load_lds(
          (glb_u32_t*)(src + tid * 16 + i * 4096),
          (lds_u32_t*)((char*)&lds[0][0] + tid * 16 + i * 4096), 16, 0, 0);
  }

  // A fragments: lane holds row (lane&15) of frag, k = (lane>>4)*8 + [0,8)
  bf16x8 a[4][KT];
#pragma unroll
  for (int rf = 0; rf < 4; rf++) {
    const float* xr =
        x + (size_t)(r0 + rf * 16 + (lane & 15)) * D_DIM + ((lane >> 4) * 8);
#pragma unroll
    for (int t = 0; t < KT; t++) {
      float4 lo = *(const float4*)(xr + t * 32);
      float4 hi = *(const float4*)(xr + t * 32 + 4);
      bf16x8 fr;
      fr[0] = (short)f2bf(lo.x); fr[1] = (short)f2bf(lo.y);
      fr[2] = (short)f2bf(lo.z); fr[3] = (short)f2bf(lo.w);
      fr[4] = (short)f2bf(hi.x); fr[5] = (short)f2bf(hi.y);
      fr[6] = (short)f2bf(hi.z); fr[7] = (short)f2bf(hi.w);
      a[rf][t] = fr;
    }
  }

  float mv[4][4];
  uint32_t mi[4][4];
#pragma unroll
  for (int rf = 0; rf < 4; rf++)
#pragma unroll
    for (int j = 0; j < 4; j++) { mv[rf][j] = 3.4e38f; mi[rf][j] = 0u; }

  const uint32_t swz = (uint32_t)((lane & 7) << 4);
  const uint32_t koff0 = (uint32_t)((lane >> 4) * 16);
  const uint32_t rowb = (uint32_t)((lane & 15) * (D_DIM * 2));

  asm volatile("s_waitcnt vmcnt(0)" ::: "memory");
  __syncthreads();

  for (int tile = 0; tile < NT; tile++) {
    const int cur = tile & 1;
    if (tile + 1 < NT) {  // stage next tile into the other buffer
      const char* src = (const char*)(cbk + (size_t)(tile + 1) * BN * D_DIM);
#pragma unroll
      for (int i = 0; i < 8; i++)
        __builtin_amdgcn_global_load_lds(
            (glb_u32_t*)(src + tid * 16 + i * 4096),
            (lds_u32_t*)((char*)&lds[cur ^ 1][0] + tid * 16 + i * 4096), 16, 0, 0);
    }
    const int cbase = ks * CPB + tile * BN;
    const char* bufp = (const char*)&lds[cur][0];
    // prefetch the 4 cnorm values for this tile
    float cn[4];
#pragma unroll
    for (int s = 0; s < 4; s++) cn[s] = cnorm[cbase + s * 16 + (lane & 15)];

#pragma unroll
    for (int s = 0; s < 4; s++) {
      f32x4 acc0 = {0.f, 0.f, 0.f, 0.f};
      f32x4 acc1 = acc0, acc2 = acc0, acc3 = acc0;
#pragma unroll
      for (int t = 0; t < KT; t++) {
        const uint32_t boff = rowb + (uint32_t)(s * 16 * D_DIM * 2) +
                              (((uint32_t)(t * 64) + koff0) ^ swz);
        const bf16x8 b = *(const bf16x8*)(bufp + boff);
        acc0 = __builtin_amdgcn_mfma_f32_16x16x32_bf16(a[0][t], b, acc0, 0, 0, 0);
        acc1 = __builtin_amdgcn_mfma_f32_16x16x32_bf16(a[1][t], b, acc1, 0, 0, 0);
        acc2 = __builtin_amdgcn_mfma_f32_16x16x32_bf16(a[2][t], b, acc2, 0, 0, 0);
        acc3 = __builtin_amdgcn_mfma_f32_16x16x32_bf16(a[3][t], b, acc3, 0, 0, 0);
      }
      const uint32_t col = (uint32_t)(cbase + s * 16 + (lane & 15));
#pragma unroll
      for (int j = 0; j < 4; j++) {
        float sc;
        sc = fmaf(-2.f, acc0[j], cn[s]);
        if (sc < mv[0][j]) { mv[0][j] = sc; mi[0][j] = col; }
        sc = fmaf(-2.f, acc1[j], cn[s]);
        if (sc < mv[1][j]) { mv[1][j] = sc; mi[1][j] = col; }
        sc = fmaf(-2.f, acc2[j], cn[s]);
        if (sc < mv[2][j]) { mv[2][j] = sc; mi[2][j] = col; }
        sc = fmaf(-2.f, acc3[j], cn[s]);
        if (sc < mv[3][j]) { mv[3][j] = sc; mi[3][j] = col; }
      }
    }
    asm volatile("s_waitcnt vmcnt(0)" ::: "memory");
    __syncthreads();
  }

  // reduce across the 16 lanes holding the same rows; acc row = (lane>>4)*4+j
#pragma unroll
  for (int rf = 0; rf < 4; rf++) {
#pragma unroll
    for (int j = 0; j < 4; j++) {
      uint32_t fb = __builtin_bit_cast(uint32_t, mv[rf][j]);
      fb = (fb & 0x80000000u) ? ~fb : (fb | 0x80000000u);  // orderable uint
      unsigned long long p =
          ((unsigned long long)fb << 32) | (unsigned long long)mi[rf][j];
#pragma unroll
      for (int m = 1; m < 16; m <<= 1) {
        unsigned long long q = __shfl_xor(p, m, 64);
        p = (q < p) ? q : p;
      }
      if ((lane & 15) == 0) {
        const int row = r0 + rf * 16 + (lane >> 4) * 4 + j;
        atomicMin(&amin[row], p);  // order-independent -> deterministic
      }
    }
  }
}

// ---------------------------------------------------------------------------
// gather: x_q = codebook[argmin], L1 loss partial (fixed-point, deterministic)
// ---------------------------------------------------------------------------
__global__ void vq_gather(const float* __restrict__ x, const float* __restrict__ cb,
                          const unsigned long long* __restrict__ amin,
                          float* __restrict__ out,
                          unsigned long long* __restrict__ lossacc) {
  const int lane = threadIdx.x & 63;
  const int wid = threadIdx.x >> 6;
  const int row0 = blockIdx.x * 64 + wid * 16;
  float lsum = 0.f;
  for (int r = 0; r < 16; r++) {
    const int row = row0 + r;
    const uint32_t idx = (uint32_t)(amin[row] & 0xFFFFFFFFull);
    const float4 e = *(const float4*)(cb + (size_t)idx * D_DIM + lane * 4);
    const float4 xv = *(const float4*)(x + (size_t)row * D_DIM + lane * 4);
    float* o = out + 1 + (size_t)row * D_DIM + lane * 4;  // +1: loss is out[0]
    o[0] = e.x; o[1] = e.y; o[2] = e.z; o[3] = e.w;
    lsum += fabsf(e.x - xv.x) + fabsf(e.y - xv.y) + fabsf(e.z - xv.z) +
            fabsf(e.w - xv.w);
  }
#pragma unroll
  for (int m = 32; m >= 1; m >>= 1) lsum += __shfl_xor(lsum, m, 64);
  if (lane == 0)
    atomicAdd(lossacc, (unsigned long long)((double)lsum * 16777216.0));
}

__global__ void vq_fin(const unsigned long long* __restrict__ lossacc,
                       float* __restrict__ out) {
  if (threadIdx.x == 0)
    out[0] = (float)((double)*lossacc * (1.0 / 16777216.0) / 8388608.0);
}

// ---------------------------------------------------------------------------
extern "C" void kernel_launch(void* const* d_in, const int* in_sizes, int n_in,
                              void* d_out, int out_size, void* d_ws, size_t ws_size,
                              hipStream_t stream) {
  const float* x = (const float*)d_in[0];
  const float* cb = (const float*)d_in[1];
  const int N = in_sizes[0] / D_DIM;  // 32768 rows

  char* ws = (char*)d_ws;
  unsigned long long* amin = (unsigned long long*)ws;                 // N*8 B
  unsigned long long* lossacc = (unsigned long long*)(ws + (size_t)N * 8);
  float* cnorm = (float*)(ws + (size_t)N * 8 + 1024);                 // K*4 B
  ushort* cbb = (ushort*)(ws + (size_t)N * 8 + 1024 + (size_t)K_CODES * 4);

  hipMemsetAsync(amin, 0xFF, (size_t)N * 8, stream);  // u64 max = +inf packed
  hipMemsetAsync(lossacc, 0, 8, stream);

  vq_prep<<<K_CODES / 4, 256, 0, stream>>>(cb, cnorm, cbb);
  vq_main<<<(N / BM) * KSPLIT, 256, 0, stream>>>(x, cbb, cnorm, amin);
  vq_gather<<<N / 64, 256, 0, stream>>>(x, cb, amin, (float*)d_out, lossacc);
  vq_fin<<<1, 64, 0, stream>>>(lossacc, (float*)d_out);
}